// Round 2
// baseline (288.604 us; speedup 1.0000x reference)
//
#include <hip/hip_runtime.h>
#include <hip/hip_bf16.h>

#define NROWS 32768
#define KCODES 8192
#define DDIM 128
#define BB 16
#define TT 2048
#define ETOT 4194304  // BB*DDIM*TT

typedef __attribute__((ext_vector_type(8))) short bf16x8;
typedef __attribute__((ext_vector_type(4))) float f32x4;

__device__ __forceinline__ void async16(char* lds_uniform, const char* g_perlane) {
    __builtin_amdgcn_global_load_lds(
        (const __attribute__((address_space(1))) unsigned int*)g_perlane,
        (__attribute__((address_space(3))) unsigned int*)lds_uniform,
        16, 0, 0);
}

// ---------------------------------------------------------------------------
// k1: normalize codebook rows, split fp32 -> bf16 hi/lo, store in MFMA
//     fragment-permuted order (per 64-code tile) so the GEMM's LDS stays
//     linear and ds_read_b128 is conflict-free.
// ---------------------------------------------------------------------------
__global__ void k_en_prep(const float* __restrict__ cb,
                          __hip_bfloat16* __restrict__ eh,
                          __hip_bfloat16* __restrict__ el) {
    int w = (blockIdx.x * blockDim.x + threadIdx.x) >> 6;  // code id
    int l = threadIdx.x & 63;
    if (w >= KCODES) return;
    const float* row = cb + (long)w * DDIM;
    float v0 = row[l], v1 = row[l + 64];
    float ss = v0 * v0 + v1 * v1;
#pragma unroll
    for (int s = 1; s < 64; s <<= 1) ss += __shfl_xor(ss, s, 64);
    float nrm = fmaxf(sqrtf(ss), 1e-12f);
    float inv = 1.0f / nrm;
    int tile = w >> 6, nf = (w >> 4) & 3, c = w & 15;
#pragma unroll
    for (int e = 0; e < 2; e++) {
        int d = l + e * 64;
        float v = (e ? v1 : v0) * inv;
        __hip_bfloat16 hi = __float2bfloat16(v);
        float hif = __bfloat162float(hi);
        __hip_bfloat16 lo = __float2bfloat16(v - hif);
        int ks = d >> 5, q = (d >> 3) & 3, dr = d & 7;
        long off = (long)tile * 8192 + (((ks * 4 + nf) * 64) + q * 16 + c) * 8 + dr;
        eh[off] = hi;
        el[off] = lo;
    }
}

// ---------------------------------------------------------------------------
// k2: transpose inputs [B,D,T] -> x [N=B*T, D] with bf16 hi/lo split.
// ---------------------------------------------------------------------------
__global__ void k_x_prep(const float* __restrict__ in,
                         __hip_bfloat16* __restrict__ xh,
                         __hip_bfloat16* __restrict__ xl) {
    __shared__ float tb[64][65];
    int bid = blockIdx.x;
    int tt0 = (bid & 31) * 64;
    int dd0 = ((bid >> 5) & 1) * 64;
    int b = bid >> 6;
    const float* base = in + (long)b * DDIM * TT;
    int tl = threadIdx.x & 63;
    int dg = threadIdx.x >> 6;
#pragma unroll
    for (int i = 0; i < 16; i++) {
        int dd = dg + i * 4;
        tb[dd][tl] = base[(long)(dd0 + dd) * TT + tt0 + tl];
    }
    __syncthreads();
    int dl = threadIdx.x & 63;
    int tg = threadIdx.x >> 6;
#pragma unroll
    for (int i = 0; i < 16; i++) {
        int t = tg + i * 4;
        float v = tb[dl][t];
        __hip_bfloat16 hi = __float2bfloat16(v);
        float hif = __bfloat162float(hi);
        __hip_bfloat16 lo = __float2bfloat16(v - hif);
        long n = (long)b * TT + tt0 + t;
        xh[n * DDIM + dd0 + dl] = hi;
        xl[n * DDIM + dd0 + dl] = lo;
    }
}

// ---------------------------------------------------------------------------
// k3: fused similarity GEMM + per-row top-2 (per column-group).
// v2: triple-buffered LDS (3x32KB), counted vmcnt (never 0 in main loop),
//     raw s_barrier (1 per iter), setprio(1) around MFMA cluster.
// ---------------------------------------------------------------------------
__device__ __forceinline__ void stage_tile(char* lb, const char* gh, const char* gl,
                                           int ou) {
    async16(lb + ou,                 gh);
    async16(lb + ou + 1024,          gh + 1024);
    async16(lb + 16384 + ou,         gl);
    async16(lb + 16384 + ou + 1024,  gl + 1024);
}

__device__ __forceinline__ void tile_compute(
    const char* __restrict__ lb, int t,
    const bf16x8 (&ahi)[2][4], const bf16x8 (&alo)[2][4],
    int l, int cg, int c16,
    float (&b1v)[8], float (&b2v)[8], int (&b1i)[8], int (&b2i)[8]) {
    f32x4 acc[2][2];
#pragma unroll
    for (int m = 0; m < 2; m++)
#pragma unroll
        for (int nf = 0; nf < 2; nf++) acc[m][nf] = (f32x4){0.f, 0.f, 0.f, 0.f};

    __builtin_amdgcn_s_setprio(1);
#pragma unroll
    for (int ks = 0; ks < 4; ks++) {
        bf16x8 bh[2], bl_[2];
#pragma unroll
        for (int nf = 0; nf < 2; nf++) {
            int chunk = (ks * 4 + (cg * 2 + nf)) * 64 + l;
            bh[nf]  = *(const bf16x8*)(lb + chunk * 16);
            bl_[nf] = *(const bf16x8*)(lb + 16384 + chunk * 16);
        }
#pragma unroll
        for (int m = 0; m < 2; m++)
#pragma unroll
            for (int nf = 0; nf < 2; nf++) {
                acc[m][nf] = __builtin_amdgcn_mfma_f32_16x16x32_bf16(ahi[m][ks], bh[nf],  acc[m][nf], 0, 0, 0);
                acc[m][nf] = __builtin_amdgcn_mfma_f32_16x16x32_bf16(alo[m][ks], bh[nf],  acc[m][nf], 0, 0, 0);
                acc[m][nf] = __builtin_amdgcn_mfma_f32_16x16x32_bf16(ahi[m][ks], bl_[nf], acc[m][nf], 0, 0, 0);
            }
    }
    __builtin_amdgcn_s_setprio(0);

    // running top-2 update (codes ascend -> strict > keeps lowest index on tie)
#pragma unroll
    for (int m = 0; m < 2; m++)
#pragma unroll
        for (int nf = 0; nf < 2; nf++) {
            int code = t * 64 + (cg * 2 + nf) * 16 + c16;
#pragma unroll
            for (int j = 0; j < 4; j++) {
                float v = acc[m][nf][j];
                int r = m * 4 + j;
                bool gt1 = v > b1v[r];
                bool gt2 = v > b2v[r];
                b2v[r] = gt1 ? b1v[r] : (gt2 ? v : b2v[r]);
                b2i[r] = gt1 ? b1i[r] : (gt2 ? code : b2i[r]);
                b1v[r] = gt1 ? v : b1v[r];
                b1i[r] = gt1 ? code : b1i[r];
            }
        }
}

__launch_bounds__(512, 1)
__global__ void k_main(const __hip_bfloat16* __restrict__ xh,
                       const __hip_bfloat16* __restrict__ xl,
                       const __hip_bfloat16* __restrict__ eh,
                       const __hip_bfloat16* __restrict__ el,
                       int* __restrict__ cand) {
    extern __shared__ char lds[];
    const int tid = threadIdx.x;
    const int l = tid & 63;
    const int w = tid >> 6;          // 0..7
    const int rg = w >> 1, cg = w & 1;
    const int c16 = l & 15, q = l >> 4;
    const long rbase = (long)blockIdx.x * 128;

    // A-fragments in registers (loaded once)
    bf16x8 ahi[2][4], alo[2][4];
#pragma unroll
    for (int m = 0; m < 2; m++) {
        long r = rbase + rg * 32 + m * 16 + c16;
        const bf16x8* ph = (const bf16x8*)(xh + r * DDIM);
        const bf16x8* pl = (const bf16x8*)(xl + r * DDIM);
#pragma unroll
        for (int ks = 0; ks < 4; ks++) {
            ahi[m][ks] = ph[ks * 4 + q];
            alo[m][ks] = pl[ks * 4 + q];
        }
    }

    float b1v[8], b2v[8];
    int b1i[8], b2i[8];
#pragma unroll
    for (int i = 0; i < 8; i++) { b1v[i] = -1e30f; b2v[i] = -1e30f; b1i[i] = 0; b2i[i] = 0; }

    const int ou = w * 2048;          // wave-uniform stage offset in 16KB half-tile
    const int pl16 = ou + l * 16;     // per-lane global offset

    const char* gh = (const char*)eh + pl16;
    const char* gl = (const char*)el + pl16;

    // prologue: stage tiles 0,1 into bufs 0,1 (prefetch distance 2)
    stage_tile(lds,         gh, gl, ou); gh += 16384; gl += 16384;
    stage_tile(lds + 32768, gh, gl, ou); gh += 16384; gl += 16384;

    char* b0 = lds;
    char* b1 = lds + 32768;
    char* b2 = lds + 65536;

    for (int t = 0; t < 126; ++t) {
        // own tile-t loads done (tile t+1's 4 stay in flight); own ds_reads of
        // tile t-1 complete; then all waves rendezvous.
        asm volatile("s_waitcnt vmcnt(4) lgkmcnt(0)\n\ts_barrier" ::: "memory");
        // stage tile t+2 into the buffer whose tile (t-1) nobody reads anymore
        stage_tile(b2, gh, gl, ou); gh += 16384; gl += 16384;
        tile_compute(b0, t, ahi, alo, l, cg, c16, b1v, b2v, b1i, b2i);
        char* tmp = b0; b0 = b1; b1 = b2; b2 = tmp;
    }
    // t = 126: nothing left to stage; tile 127's 4 loads may remain in flight
    asm volatile("s_waitcnt vmcnt(4) lgkmcnt(0)\n\ts_barrier" ::: "memory");
    tile_compute(b0, 126, ahi, alo, l, cg, c16, b1v, b2v, b1i, b2i);
    { char* tmp = b0; b0 = b1; b1 = b2; b2 = tmp; }
    // t = 127: final drain
    asm volatile("s_waitcnt vmcnt(0) lgkmcnt(0)\n\ts_barrier" ::: "memory");
    tile_compute(b0, 127, ahi, alo, l, cg, c16, b1v, b2v, b1i, b2i);

    // merge top-2 across the 16 lanes of each row group (butterfly)
#pragma unroll
    for (int s = 1; s < 16; s <<= 1) {
#pragma unroll
        for (int i = 0; i < 8; i++) {
            float o1v = __shfl_xor(b1v[i], s, 64);
            int   o1i = __shfl_xor(b1i[i], s, 64);
            float o2v = __shfl_xor(b2v[i], s, 64);
            int   o2i = __shfl_xor(b2i[i], s, 64);
            bool t1 = (o1v > b1v[i]) || (o1v == b1v[i] && o1i < b1i[i]);
            float f1v = t1 ? o1v : b1v[i]; int f1i = t1 ? o1i : b1i[i];
            float c2v = t1 ? b1v[i] : o1v; int c2i = t1 ? b1i[i] : o1i;
            float d2v = t1 ? o2v : b2v[i]; int d2i = t1 ? o2i : b2i[i];
            bool t2 = (c2v > d2v) || (c2v == d2v && c2i < d2i);
            b2v[i] = t2 ? c2v : d2v; b2i[i] = t2 ? c2i : d2i;
            b1v[i] = f1v; b1i[i] = f1i;
        }
    }
    if (c16 == 0) {
#pragma unroll
        for (int m = 0; m < 2; m++)
#pragma unroll
            for (int j = 0; j < 4; j++) {
                long n = rbase + rg * 32 + m * 16 + q * 4 + j;
                int* cp = cand + n * 4 + cg * 2;
                cp[0] = b1i[m * 4 + j];
                cp[1] = b2i[m * 4 + j];
            }
    }
}

// ---------------------------------------------------------------------------
// k4: fp64 exact re-evaluation of the 4 candidates per row; writes final
//     index (int to ws, float to d_out index region). One wave per row.
// ---------------------------------------------------------------------------
__global__ void k_refine(const float* __restrict__ in, const float* __restrict__ cb,
                         const int* __restrict__ cand, int* __restrict__ idx_out,
                         float* __restrict__ idx_f) {
    int n = (blockIdx.x * blockDim.x + threadIdx.x) >> 6;
    int l = threadIdx.x & 63;
    if (n >= NROWS) return;
    int b = n >> 11, t = n & 2047;
    const float* xb = in + (long)b * DDIM * TT + t;
    double x0 = xb[(long)l * TT];
    double x1 = xb[(long)(l + 64) * TT];
    double best = -1e300;
    int bi = 0x7fffffff;
#pragma unroll
    for (int kk = 0; kk < 4; ++kk) {
        int c = cand[n * 4 + kk];
        const float* e = cb + (long)c * DDIM;
        double e0 = e[l], e1 = e[l + 64];
        double dot = x0 * e0 + x1 * e1;
        double nrm = e0 * e0 + e1 * e1;
#pragma unroll
        for (int s = 1; s < 64; s <<= 1) {
            dot += __shfl_xor(dot, s, 64);
            nrm += __shfl_xor(nrm, s, 64);
        }
        double sv = dot / fmax(sqrt(nrm), 1e-12);
        if (sv > best || (sv == best && c < bi)) { best = sv; bi = c; }
    }
    if (l == 0) {
        idx_out[n] = bi;
        idx_f[n] = (float)bi;
    }
}

// ---------------------------------------------------------------------------
// k5: write out = x + (q - x) (fp32 STE emulation) in [B,D,T] order and
//     accumulate per-block fp64 partial sums of (q-x)^2.
// ---------------------------------------------------------------------------
__global__ void k_out_loss(const float* __restrict__ in, const float* __restrict__ cb,
                           const int* __restrict__ idx, float* __restrict__ out,
                           double* __restrict__ part) {
    __shared__ double sd[256];
    double acc = 0.0;
    for (long e = (long)blockIdx.x * blockDim.x + threadIdx.x; e < ETOT;
         e += (long)gridDim.x * blockDim.x) {
        long t = e & 2047;
        long d = (e >> 11) & 127;
        long b = e >> 18;
        float xv = in[e];
        int n = (int)((b << 11) | t);
        float qv = cb[(long)idx[n] * DDIM + d];
        float diff = qv - xv;
        out[e] = xv + diff;
        acc += (double)diff * (double)diff;
    }
    sd[threadIdx.x] = acc;
    __syncthreads();
    for (int s = 128; s > 0; s >>= 1) {
        if (threadIdx.x < s) sd[threadIdx.x] += sd[threadIdx.x + s];
        __syncthreads();
    }
    if (threadIdx.x == 0) part[blockIdx.x] = sd[0];
}

__global__ void k_loss_final(const double* __restrict__ part, int np,
                             float* __restrict__ loss) {
    __shared__ double sd[256];
    double a = 0.0;
    for (int i = threadIdx.x; i < np; i += 256) a += part[i];
    sd[threadIdx.x] = a;
    __syncthreads();
    for (int s = 128; s > 0; s >>= 1) {
        if (threadIdx.x < s) sd[threadIdx.x] += sd[threadIdx.x + s];
        __syncthreads();
    }
    if (threadIdx.x == 0) {
        float m = (float)(sd[0] / (double)ETOT);
        loss[0] = m + 0.02f * m;  // q_latent + commitment * e_latent (both = mse)
    }
}

// ---------------------------------------------------------------------------
extern "C" void kernel_launch(void* const* d_in, const int* in_sizes, int n_in,
                              void* d_out, int out_size, void* d_ws, size_t ws_size,
                              hipStream_t stream) {
    const float* inputs = (const float*)d_in[0];   // [16,128,2048] fp32
    const float* cb     = (const float*)d_in[1];   // [8192,128]    fp32
    float* outf = (float*)d_out;                   // [loss | out(B,D,T) | idx]

    char* ws = (char*)d_ws;
    __hip_bfloat16* xh = (__hip_bfloat16*)ws; ws += (long)NROWS * DDIM * 2;
    __hip_bfloat16* xl = (__hip_bfloat16*)ws; ws += (long)NROWS * DDIM * 2;
    __hip_bfloat16* eh = (__hip_bfloat16*)ws; ws += (long)KCODES * DDIM * 2;
    __hip_bfloat16* el = (__hip_bfloat16*)ws; ws += (long)KCODES * DDIM * 2;
    int* cand   = (int*)ws;    ws += (long)NROWS * 4 * 4;
    int* idx    = (int*)ws;    ws += (long)NROWS * 4;
    double* part = (double*)ws; ws += 2048 * 8;

    // 96 KB dynamic LDS needs the opt-in attribute (idempotent, capture-safe)
    hipFuncSetAttribute((const void*)k_main,
                        hipFuncAttributeMaxDynamicSharedMemorySize, 98304);

    k_en_prep<<<dim3(2048), dim3(256), 0, stream>>>(cb, eh, el);
    k_x_prep<<<dim3(1024), dim3(256), 0, stream>>>(inputs, xh, xl);
    k_main<<<dim3(256), dim3(512), 98304, stream>>>(xh, xl, eh, el, cand);
    k_refine<<<dim3(8192), dim3(256), 0, stream>>>(inputs, cb, cand, idx,
                                                   outf + 1 + (long)ETOT);
    k_out_loss<<<dim3(2048), dim3(256), 0, stream>>>(inputs, cb, idx, outf + 1, part);
    k_loss_final<<<dim3(1), dim3(256), 0, stream>>>(part, 2048, outf);
}

// Round 3
// 245.421 us; speedup vs baseline: 1.1760x; 1.1760x over previous
//
#include <hip/hip_runtime.h>
#include <hip/hip_bf16.h>

#define NROWS 32768
#define KCODES 8192
#define DDIM 128
#define BB 16
#define TT 2048
#define ETOT 4194304  // BB*DDIM*TT
#define BUFSZ 65536   // 128-code tile: 32KB eh + 32KB el

typedef __attribute__((ext_vector_type(8))) short bf16x8;
typedef __attribute__((ext_vector_type(4))) float f32x4;

__device__ __forceinline__ void async16(char* lds_uniform, const char* g_perlane) {
    __builtin_amdgcn_global_load_lds(
        (const __attribute__((address_space(1))) unsigned int*)g_perlane,
        (__attribute__((address_space(3))) unsigned int*)lds_uniform,
        16, 0, 0);
}

// ---------------------------------------------------------------------------
// k1: normalize codebook rows, split fp32 -> bf16 hi/lo, store in MFMA
//     fragment-permuted order (per 64-code block) so LDS stays linear and
//     ds_read_b128 is conflict-free. Used as the A-operand (codes = M).
// elem offset = blk64*8192 + ((ks*4+nf)*64 + q*16 + c)*8 + dr
// ---------------------------------------------------------------------------
__global__ void k_en_prep(const float* __restrict__ cb,
                          __hip_bfloat16* __restrict__ eh,
                          __hip_bfloat16* __restrict__ el) {
    int w = (blockIdx.x * blockDim.x + threadIdx.x) >> 6;  // code id
    int l = threadIdx.x & 63;
    if (w >= KCODES) return;
    const float* row = cb + (long)w * DDIM;
    float v0 = row[l], v1 = row[l + 64];
    float ss = v0 * v0 + v1 * v1;
#pragma unroll
    for (int s = 1; s < 64; s <<= 1) ss += __shfl_xor(ss, s, 64);
    float nrm = fmaxf(sqrtf(ss), 1e-12f);
    float inv = 1.0f / nrm;
    int blk = w >> 6, nf = (w >> 4) & 3, c = w & 15;
#pragma unroll
    for (int e = 0; e < 2; e++) {
        int d = l + e * 64;
        float v = (e ? v1 : v0) * inv;
        __hip_bfloat16 hi = __float2bfloat16(v);
        float hif = __bfloat162float(hi);
        __hip_bfloat16 lo = __float2bfloat16(v - hif);
        int ks = d >> 5, q = (d >> 3) & 3, dr = d & 7;
        long off = (long)blk * 8192 + (((ks * 4 + nf) * 64) + q * 16 + c) * 8 + dr;
        eh[off] = hi;
        el[off] = lo;
    }
}

// ---------------------------------------------------------------------------
// k2: transpose inputs [B,D,T] -> x [N=B*T, D] row-major with bf16 hi/lo split.
// ---------------------------------------------------------------------------
__global__ void k_x_prep(const float* __restrict__ in,
                         __hip_bfloat16* __restrict__ xh,
                         __hip_bfloat16* __restrict__ xl) {
    __shared__ float tb[64][65];
    int bid = blockIdx.x;
    int tt0 = (bid & 31) * 64;
    int dd0 = ((bid >> 5) & 1) * 64;
    int b = bid >> 6;
    const float* base = in + (long)b * DDIM * TT;
    int tl = threadIdx.x & 63;
    int dg = threadIdx.x >> 6;
#pragma unroll
    for (int i = 0; i < 16; i++) {
        int dd = dg + i * 4;
        tb[dd][tl] = base[(long)(dd0 + dd) * TT + tt0 + tl];
    }
    __syncthreads();
    int dl = threadIdx.x & 63;
    int tg = threadIdx.x >> 6;
#pragma unroll
    for (int i = 0; i < 16; i++) {
        int t = tg + i * 4;
        float v = tb[dl][t];
        __hip_bfloat16 hi = __float2bfloat16(v);
        float hif = __bfloat162float(hi);
        __hip_bfloat16 lo = __float2bfloat16(v - hif);
        long n = (long)b * TT + tt0 + t;
        xh[n * DDIM + dd0 + dl] = hi;
        xl[n * DDIM + dd0 + dl] = lo;
    }
}

// ---------------------------------------------------------------------------
// k3 v3: TRANSPOSED similarity GEMM + per-row top-2 via quad-reduce.
// C[code][xrow]: A = codes (streamed through LDS), B = x-rows (registers).
// 256 blocks x 512 thr; block = 128 xrows; tile = 128 codes, 64 tiles.
// 8 waves = 2 xg (64 xrows) x 4 cg (32 codes). Wave = 32 codes x 64 xrows.
// Per lane: each f32x4 = 4 CODES of one xrow -> quad-reduce then top-2 insert.
// ---------------------------------------------------------------------------
__launch_bounds__(512, 2)
__global__ void k_main(const __hip_bfloat16* __restrict__ xh,
                       const __hip_bfloat16* __restrict__ xl,
                       const __hip_bfloat16* __restrict__ eh,
                       const __hip_bfloat16* __restrict__ el,
                       int* __restrict__ cand) {
    extern __shared__ char lds[];
    const int tid = threadIdx.x;
    const int l = tid & 63;
    const int w = tid >> 6;          // 0..7
    const int xg = w >> 2;           // 0..1 : xrow group of 64
    const int cg = w & 3;            // 0..3 : code group of 32 within tile
    const int col = l & 15, kq = l >> 4;
    const long rbase = (long)blockIdx.x * 128 + xg * 64;

    // B-operand x-fragments in registers (loaded once): nf = xrow-frag 0..3
    bf16x8 bxh[4][4], bxl[4][4];
#pragma unroll
    for (int nf = 0; nf < 4; nf++) {
        long n = rbase + nf * 16 + col;
        const bf16x8* ph = (const bf16x8*)(xh + n * DDIM);
        const bf16x8* pl = (const bf16x8*)(xl + n * DDIM);
#pragma unroll
        for (int ks = 0; ks < 4; ks++) {
            bxh[nf][ks] = ph[ks * 4 + kq];
            bxl[nf][ks] = pl[ks * 4 + kq];
        }
    }

    // per-lane top-2 per nf (one xrow each)
    float b1v[4], b2v[4];
    int b1i[4], b2i[4];
#pragma unroll
    for (int i = 0; i < 4; i++) { b1v[i] = -1e30f; b2v[i] = -1e30f; b1i[i] = 0; b2i[i] = 0; }

    // staging pointers: per tile, wave w copies bytes [w*4096, w*4096+4096) of
    // each of eh/el's 32KB tile chunk; per-lane src offset l*16.
    const char* ghp = (const char*)eh + w * 4096 + l * 16;
    const char* glp = (const char*)el + w * 4096 + l * 16;
    const int woff = w * 4096;

    // prologue: stage tile 0 into buf 0
#pragma unroll
    for (int i = 0; i < 4; i++) {
        async16(lds + woff + i * 1024,         ghp + i * 1024);
        async16(lds + 32768 + woff + i * 1024, glp + i * 1024);
    }
    ghp += 32768; glp += 32768;

    for (int t = 0; t < 64; ++t) {
        asm volatile("s_waitcnt vmcnt(0) lgkmcnt(0)\n\ts_barrier" ::: "memory");
        if (t < 63) {
            char* nb = lds + ((t & 1) ^ 1) * BUFSZ;
#pragma unroll
            for (int i = 0; i < 4; i++) {
                async16(nb + woff + i * 1024,         ghp + i * 1024);
                async16(nb + 32768 + woff + i * 1024, glp + i * 1024);
            }
            ghp += 32768; glp += 32768;
        }

        const char* buf = lds + (t & 1) * BUFSZ;
        f32x4 acc[2][4];
#pragma unroll
        for (int mq = 0; mq < 2; mq++)
#pragma unroll
            for (int nf = 0; nf < 4; nf++) acc[mq][nf] = (f32x4){0.f, 0.f, 0.f, 0.f};

#pragma unroll
        for (int mq = 0; mq < 2; mq++) {
            const int c0 = cg * 32 + mq * 16;
            const char* bhp = buf + (c0 >> 6) * 16384 + ((c0 >> 4) & 3) * 1024 + l * 16;
            const char* blp = bhp + 32768;
#pragma unroll
            for (int ks = 0; ks < 4; ks++) {
                bf16x8 ah = *(const bf16x8*)(bhp + ks * 4096);
                bf16x8 al = *(const bf16x8*)(blp + ks * 4096);
#pragma unroll
                for (int nf = 0; nf < 4; nf++) {
                    acc[mq][nf] = __builtin_amdgcn_mfma_f32_16x16x32_bf16(ah, bxh[nf][ks], acc[mq][nf], 0, 0, 0);
                    acc[mq][nf] = __builtin_amdgcn_mfma_f32_16x16x32_bf16(al, bxh[nf][ks], acc[mq][nf], 0, 0, 0);
                    acc[mq][nf] = __builtin_amdgcn_mfma_f32_16x16x32_bf16(ah, bxl[nf][ks], acc[mq][nf], 0, 0, 0);
                }
            }
        }

        // quad-reduce (4 codes -> max+index) then top-2 insert, per (mq,nf)
#pragma unroll
        for (int mq = 0; mq < 2; mq++) {
            const int cb0 = t * 128 + cg * 32 + mq * 16 + kq * 4;
#pragma unroll
            for (int nf = 0; nf < 4; nf++) {
                f32x4 a = acc[mq][nf];
                float v = fmaxf(fmaxf(a[0], a[1]), fmaxf(a[2], a[3]));
                int ci = (v == a[2]) ? cb0 + 2 : cb0 + 3;
                ci = (v == a[1]) ? cb0 + 1 : ci;
                ci = (v == a[0]) ? cb0 : ci;     // ties -> lowest code
                bool gt1 = v > b1v[nf];
                bool gt2 = v > b2v[nf];
                b2v[nf] = gt1 ? b1v[nf] : (gt2 ? v : b2v[nf]);
                b2i[nf] = gt1 ? b1i[nf] : (gt2 ? ci : b2i[nf]);
                b1v[nf] = gt1 ? v : b1v[nf];
                b1i[nf] = gt1 ? ci : b1i[nf];
            }
        }
    }

    // merge top-2 across the 4 lanes sharing one xrow (l ^ 16, l ^ 32)
#pragma unroll
    for (int s = 16; s < 64; s <<= 1) {
#pragma unroll
        for (int i = 0; i < 4; i++) {
            float o1v = __shfl_xor(b1v[i], s, 64);
            int   o1i = __shfl_xor(b1i[i], s, 64);
            float o2v = __shfl_xor(b2v[i], s, 64);
            int   o2i = __shfl_xor(b2i[i], s, 64);
            bool t1 = (o1v > b1v[i]) || (o1v == b1v[i] && o1i < b1i[i]);
            float f1v = t1 ? o1v : b1v[i]; int f1i = t1 ? o1i : b1i[i];
            float c2v = t1 ? b1v[i] : o1v; int c2i = t1 ? b1i[i] : o1i;
            float d2v = t1 ? o2v : b2v[i]; int d2i = t1 ? o2i : b2i[i];
            bool t2 = (c2v > d2v) || (c2v == d2v && c2i < d2i);
            b2v[i] = t2 ? c2v : d2v; b2i[i] = t2 ? c2i : d2i;
            b1v[i] = f1v; b1i[i] = f1i;
        }
    }

    __syncthreads();  // all tiles consumed; reuse LDS for cross-wave merge
    if (l < 16) {
#pragma unroll
        for (int nf = 0; nf < 4; nf++) {
            int row = xg * 64 + nf * 16 + l;
            float4* p = (float4*)lds + row * 4 + cg;
            *p = make_float4(b1v[nf], __int_as_float(b1i[nf]),
                             b2v[nf], __int_as_float(b2i[nf]));
        }
    }
    __syncthreads();
    if (tid < 128) {
        float sv[4] = {-1e30f, -1e30f, -1e30f, -1e30f};
        int   si[4] = {0x7fffffff, 0x7fffffff, 0x7fffffff, 0x7fffffff};
#pragma unroll
        for (int c = 0; c < 4; c++) {
            float4 qd = ((float4*)lds)[tid * 4 + c];
#pragma unroll
            for (int h = 0; h < 2; h++) {
                float v = h ? qd.z : qd.x;
                int   i = __float_as_int(h ? qd.w : qd.y);
#pragma unroll
                for (int k = 0; k < 4; k++) {
                    bool sw = (v > sv[k]) || (v == sv[k] && i < si[k]);
                    float tv = sw ? v : sv[k]; int ti = sw ? i : si[k];
                    v = sw ? sv[k] : v;        i = sw ? si[k] : i;
                    sv[k] = tv; si[k] = ti;
                }
            }
        }
        long n = (long)blockIdx.x * 128 + tid;
#pragma unroll
        for (int k = 0; k < 4; k++) cand[n * 4 + k] = si[k];
    }
}

// ---------------------------------------------------------------------------
// k4: fp64 exact re-evaluation of the 4 candidates per row; writes final
//     index (int to ws, float to d_out index region). One wave per row.
// ---------------------------------------------------------------------------
__global__ void k_refine(const float* __restrict__ in, const float* __restrict__ cb,
                         const int* __restrict__ cand, int* __restrict__ idx_out,
                         float* __restrict__ idx_f) {
    int n = (blockIdx.x * blockDim.x + threadIdx.x) >> 6;
    int l = threadIdx.x & 63;
    if (n >= NROWS) return;
    int b = n >> 11, t = n & 2047;
    const float* xb = in + (long)b * DDIM * TT + t;
    double x0 = xb[(long)l * TT];
    double x1 = xb[(long)(l + 64) * TT];
    double best = -1e300;
    int bi = 0x7fffffff;
#pragma unroll
    for (int kk = 0; kk < 4; ++kk) {
        int c = cand[n * 4 + kk];
        const float* e = cb + (long)c * DDIM;
        double e0 = e[l], e1 = e[l + 64];
        double dot = x0 * e0 + x1 * e1;
        double nrm = e0 * e0 + e1 * e1;
#pragma unroll
        for (int s = 1; s < 64; s <<= 1) {
            dot += __shfl_xor(dot, s, 64);
            nrm += __shfl_xor(nrm, s, 64);
        }
        double sv = dot / fmax(sqrt(nrm), 1e-12);
        if (sv > best || (sv == best && c < bi)) { best = sv; bi = c; }
    }
    if (l == 0) {
        idx_out[n] = bi;
        idx_f[n] = (float)bi;
    }
}

// ---------------------------------------------------------------------------
// k5: write out = x + (q - x) (fp32 STE emulation) in [B,D,T] order and
//     accumulate per-block fp64 partial sums of (q-x)^2.
// ---------------------------------------------------------------------------
__global__ void k_out_loss(const float* __restrict__ in, const float* __restrict__ cb,
                           const int* __restrict__ idx, float* __restrict__ out,
                           double* __restrict__ part) {
    __shared__ double sd[256];
    double acc = 0.0;
    for (long e = (long)blockIdx.x * blockDim.x + threadIdx.x; e < ETOT;
         e += (long)gridDim.x * blockDim.x) {
        long t = e & 2047;
        long d = (e >> 11) & 127;
        long b = e >> 18;
        float xv = in[e];
        int n = (int)((b << 11) | t);
        float qv = cb[(long)idx[n] * DDIM + d];
        float diff = qv - xv;
        out[e] = xv + diff;
        acc += (double)diff * (double)diff;
    }
    sd[threadIdx.x] = acc;
    __syncthreads();
    for (int s = 128; s > 0; s >>= 1) {
        if (threadIdx.x < s) sd[threadIdx.x] += sd[threadIdx.x + s];
        __syncthreads();
    }
    if (threadIdx.x == 0) part[blockIdx.x] = sd[0];
}

__global__ void k_loss_final(const double* __restrict__ part, int np,
                             float* __restrict__ loss) {
    __shared__ double sd[256];
    double a = 0.0;
    for (int i = threadIdx.x; i < np; i += 256) a += part[i];
    sd[threadIdx.x] = a;
    __syncthreads();
    for (int s = 128; s > 0; s >>= 1) {
        if (threadIdx.x < s) sd[threadIdx.x] += sd[threadIdx.x + s];
        __syncthreads();
    }
    if (threadIdx.x == 0) {
        float m = (float)(sd[0] / (double)ETOT);
        loss[0] = m + 0.02f * m;  // q_latent + commitment * e_latent (both = mse)
    }
}

// ---------------------------------------------------------------------------
extern "C" void kernel_launch(void* const* d_in, const int* in_sizes, int n_in,
                              void* d_out, int out_size, void* d_ws, size_t ws_size,
                              hipStream_t stream) {
    const float* inputs = (const float*)d_in[0];   // [16,128,2048] fp32
    const float* cb     = (const float*)d_in[1];   // [8192,128]    fp32
    float* outf = (float*)d_out;                   // [loss | out(B,D,T) | idx]

    char* ws = (char*)d_ws;
    __hip_bfloat16* xh = (__hip_bfloat16*)ws; ws += (long)NROWS * DDIM * 2;
    __hip_bfloat16* xl = (__hip_bfloat16*)ws; ws += (long)NROWS * DDIM * 2;
    __hip_bfloat16* eh = (__hip_bfloat16*)ws; ws += (long)KCODES * DDIM * 2;
    __hip_bfloat16* el = (__hip_bfloat16*)ws; ws += (long)KCODES * DDIM * 2;
    int* cand   = (int*)ws;    ws += (long)NROWS * 4 * 4;
    int* idx    = (int*)ws;    ws += (long)NROWS * 4;
    double* part = (double*)ws; ws += 2048 * 8;

    // 128 KB dynamic LDS needs the opt-in attribute (idempotent, capture-safe)
    hipFuncSetAttribute((const void*)k_main,
                        hipFuncAttributeMaxDynamicSharedMemorySize, 131072);

    k_en_prep<<<dim3(2048), dim3(256), 0, stream>>>(cb, eh, el);
    k_x_prep<<<dim3(1024), dim3(256), 0, stream>>>(inputs, xh, xl);
    k_main<<<dim3(256), dim3(512), 131072, stream>>>(xh, xl, eh, el, cand);
    k_refine<<<dim3(8192), dim3(256), 0, stream>>>(inputs, cb, cand, idx,
                                                   outf + 1 + (long)ETOT);
    k_out_loss<<<dim3(2048), dim3(256), 0, stream>>>(inputs, cb, idx, outf + 1, part);
    k_loss_final<<<dim3(1), dim3(256), 0, stream>>>(part, 2048, outf);
}

// Round 4
// 232.810 us; speedup vs baseline: 1.2397x; 1.0542x over previous
//
#include <hip/hip_runtime.h>
#include <hip/hip_bf16.h>

#define NROWS 32768
#define KCODES 8192
#define DDIM 128
#define TT 2048
#define ETOT 4194304  // 16*128*2048

typedef __attribute__((ext_vector_type(8))) _Float16 f16x8;
typedef __attribute__((ext_vector_type(4))) float f32x4;

__device__ __forceinline__ void async16(char* lds_uniform, const char* g_perlane) {
    __builtin_amdgcn_global_load_lds(
        (const __attribute__((address_space(1))) unsigned int*)g_perlane,
        (__attribute__((address_space(3))) unsigned int*)lds_uniform,
        16, 0, 0);
}

// ---------------------------------------------------------------------------
// k1: normalize codebook rows, fp32 -> fp16, store in MFMA A-fragment order
//     per 64-code tile (16KB each) so LDS stays linear, ds_read_b128 clean.
// code w: tile=w>>6, cg=(w>>4)&3, c=w&15 ; dim d: ks=d>>5, kq=(d>>3)&3, dr=d&7
// elem off = tile*8192 + ((ks*4+cg)*64 + kq*16 + c)*8 + dr
// ---------------------------------------------------------------------------
__global__ void k_en_prep(const float* __restrict__ cb,
                          _Float16* __restrict__ eh) {
    int w = (blockIdx.x * blockDim.x + threadIdx.x) >> 6;  // code id
    int l = threadIdx.x & 63;
    if (w >= KCODES) return;
    const float* row = cb + (long)w * DDIM;
    float v0 = row[l], v1 = row[l + 64];
    float ss = v0 * v0 + v1 * v1;
#pragma unroll
    for (int s = 1; s < 64; s <<= 1) ss += __shfl_xor(ss, s, 64);
    float inv = 1.0f / fmaxf(sqrtf(ss), 1e-12f);
    int tile = w >> 6, cg = (w >> 4) & 3, c = w & 15;
#pragma unroll
    for (int e = 0; e < 2; e++) {
        int d = l + e * 64;
        float v = (e ? v1 : v0) * inv;
        int ks = d >> 5, kq = (d >> 3) & 3, dr = d & 7;
        long off = (long)tile * 8192 + (((ks * 4 + cg) * 64) + kq * 16 + c) * 8 + dr;
        eh[off] = (_Float16)v;
    }
}

// ---------------------------------------------------------------------------
// k2: transpose inputs [B,D,T] -> xh [N=B*T, D] row-major fp16.
// ---------------------------------------------------------------------------
__global__ void k_x_prep(const float* __restrict__ in,
                         _Float16* __restrict__ xh) {
    __shared__ float tb[64][65];
    int bid = blockIdx.x;
    int tt0 = (bid & 31) * 64;
    int dd0 = ((bid >> 5) & 1) * 64;
    int b = bid >> 6;
    const float* base = in + (long)b * DDIM * TT;
    int tl = threadIdx.x & 63;
    int dg = threadIdx.x >> 6;
#pragma unroll
    for (int i = 0; i < 16; i++) {
        int dd = dg + i * 4;
        tb[dd][tl] = base[(long)(dd0 + dd) * TT + tt0 + tl];
    }
    __syncthreads();
    int dl = threadIdx.x & 63;
    int tg = threadIdx.x >> 6;
#pragma unroll
    for (int i = 0; i < 16; i++) {
        int t = tg + i * 4;
        long n = (long)b * TT + tt0 + t;
        xh[n * DDIM + dd0 + dl] = (_Float16)tb[dl][t];
    }
}

// ---------------------------------------------------------------------------
// k3 v4: fp16 single-product similarity GEMM + hardened candidate selection.
// C[code][xrow]. 512 blocks x 512 thr (8 waves = 2 xg x 4 cg), 64 xrows/blk.
// Tile = 64 codes (16KB eh), 128 tiles, TRIPLE-buffered LDS (48KB), counted
// vmcnt (round-2 proven skeleton). Per lane: quad-top-2 -> top-3 (+2nd-stream
// top-1); epilogue merges 64 entries/row -> global top-4 -> cand[n][4].
// ---------------------------------------------------------------------------
__launch_bounds__(512, 4)
__global__ void k_main(const _Float16* __restrict__ xh,
                       const _Float16* __restrict__ eh,
                       int* __restrict__ cand) {
    extern __shared__ char lds[];
    const int tid = threadIdx.x;
    const int l = tid & 63;
    const int w = tid >> 6;          // 0..7
    const int xg = w >> 2;           // 0..1 : xrow group of 32
    const int cg = w & 3;            // 0..3 : 16-code group within tile
    const int col = l & 15, kq = l >> 4;
    const long rbase = (long)blockIdx.x * 64;

    // B-operand x-fragments in registers (loaded once)
    f16x8 bx[2][4];
#pragma unroll
    for (int nf = 0; nf < 2; nf++) {
        long n = rbase + xg * 32 + nf * 16 + col;
#pragma unroll
        for (int ks = 0; ks < 4; ks++)
            bx[nf][ks] = *(const f16x8*)(xh + n * DDIM + ks * 32 + kq * 8);
    }

    float t1v[2], t2v[2], t3v[2], u1v[2];
    int   t1i[2], t2i[2], t3i[2], u1i[2];
#pragma unroll
    for (int i = 0; i < 2; i++) {
        t1v[i] = t2v[i] = t3v[i] = u1v[i] = -1e30f;
        t1i[i] = t2i[i] = t3i[i] = u1i[i] = 0;
    }

    const char* gsrc = (const char*)eh + tid * 16;

    // prologue: stage tiles 0,1 (2 async16 each; triple buffer, dist-2)
    async16(lds + tid * 16,                 gsrc);
    async16(lds + 8192 + tid * 16,          gsrc + 8192);
    async16(lds + 16384 + tid * 16,         gsrc + 16384);
    async16(lds + 16384 + 8192 + tid * 16,  gsrc + 16384 + 8192);
    gsrc += 32768;

    char* b0 = lds;
    char* b1 = lds + 16384;
    char* b2 = lds + 32768;

    for (int t = 0; t < 128; ++t) {
        if (t < 126) {
            asm volatile("s_waitcnt vmcnt(2) lgkmcnt(0)\n\ts_barrier" ::: "memory");
            async16(b2 + tid * 16,        gsrc);
            async16(b2 + 8192 + tid * 16, gsrc + 8192);
            gsrc += 16384;
        } else if (t == 126) {
            asm volatile("s_waitcnt vmcnt(2) lgkmcnt(0)\n\ts_barrier" ::: "memory");
        } else {
            asm volatile("s_waitcnt vmcnt(0) lgkmcnt(0)\n\ts_barrier" ::: "memory");
        }

        f32x4 acc[2];
        acc[0] = (f32x4){0.f, 0.f, 0.f, 0.f};
        acc[1] = (f32x4){0.f, 0.f, 0.f, 0.f};
#pragma unroll
        for (int ks = 0; ks < 4; ks++) {
            f16x8 ah = *(const f16x8*)(b0 + ((ks * 4 + cg) * 64 + l) * 16);
            acc[0] = __builtin_amdgcn_mfma_f32_16x16x32_f16(ah, bx[0][ks], acc[0], 0, 0, 0);
            acc[1] = __builtin_amdgcn_mfma_f32_16x16x32_f16(ah, bx[1][ks], acc[1], 0, 0, 0);
        }

        // quad-top-2 then inserts (strict > => lowest code kept on ties)
#pragma unroll
        for (int nf = 0; nf < 2; nf++) {
            f32x4 a = acc[nf];
            int cb0 = t * 64 + cg * 16 + kq * 4;
            bool g01 = a[1] > a[0];
            float p01v = fmaxf(a[0], a[1]); int p01i = g01 ? cb0 + 1 : cb0;
            float q01v = fminf(a[0], a[1]); int q01i = g01 ? cb0 : cb0 + 1;
            bool g23 = a[3] > a[2];
            float p23v = fmaxf(a[2], a[3]); int p23i = g23 ? cb0 + 3 : cb0 + 2;
            float q23v = fminf(a[2], a[3]); int q23i = g23 ? cb0 + 2 : cb0 + 3;
            bool gw = p23v > p01v;
            float w1v = fmaxf(p01v, p23v); int w1i = gw ? p23i : p01i;
            float cav = gw ? p01v : p23v;  int cai = gw ? p01i : p23i;
            float cbv = gw ? q23v : q01v;  int cbi = gw ? q23i : q01i;
            float w2v = fmaxf(cav, cbv);   int w2i = (cbv > cav) ? cbi : cai;
            // insert w1 into sorted top-3
            bool i1 = w1v > t1v[nf], i2 = w1v > t2v[nf], i3 = w1v > t3v[nf];
            t3v[nf] = i2 ? t2v[nf] : (i3 ? w1v : t3v[nf]);
            t3i[nf] = i2 ? t2i[nf] : (i3 ? w1i : t3i[nf]);
            t2v[nf] = i1 ? t1v[nf] : (i2 ? w1v : t2v[nf]);
            t2i[nf] = i1 ? t1i[nf] : (i2 ? w1i : t2i[nf]);
            t1v[nf] = i1 ? w1v : t1v[nf];
            t1i[nf] = i1 ? w1i : t1i[nf];
            // quad-second stream: top-1 only
            bool j1 = w2v > u1v[nf];
            u1v[nf] = j1 ? w2v : u1v[nf];
            u1i[nf] = j1 ? w2i : u1i[nf];
        }

        char* tmp = b0; b0 = b1; b1 = b2; b2 = tmp;
    }

    __syncthreads();  // staging + reads done; reuse LDS for candidate merge

    // each lane writes its 4 entries: [row][entry=(cg*4+kq)*4+j] as float2
    float2* mrg = (float2*)lds;
#pragma unroll
    for (int nf = 0; nf < 2; nf++) {
        int row = xg * 32 + nf * 16 + col;
        int e0 = (cg * 4 + kq) * 4;
        mrg[row * 64 + e0 + 0] = make_float2(t1v[nf], __int_as_float(t1i[nf]));
        mrg[row * 64 + e0 + 1] = make_float2(t2v[nf], __int_as_float(t2i[nf]));
        mrg[row * 64 + e0 + 2] = make_float2(t3v[nf], __int_as_float(t3i[nf]));
        mrg[row * 64 + e0 + 3] = make_float2(u1v[nf], __int_as_float(u1i[nf]));
    }
    __syncthreads();

    if (tid < 64) {
        float sv[4] = {-1e30f, -1e30f, -1e30f, -1e30f};
        int   si[4] = {0x7fffffff, 0x7fffffff, 0x7fffffff, 0x7fffffff};
#pragma unroll 8
        for (int e = 0; e < 64; e++) {
            float2 p = mrg[tid * 64 + e];
            float v = p.x; int i = __float_as_int(p.y);
#pragma unroll
            for (int k = 0; k < 4; k++) {
                bool sw = (v > sv[k]) || (v == sv[k] && i < si[k]);
                float tv = sw ? v : sv[k]; int ti = sw ? i : si[k];
                v = sw ? sv[k] : v;        i = sw ? si[k] : i;
                sv[k] = tv; si[k] = ti;
            }
        }
        long n = rbase + tid;
#pragma unroll
        for (int k = 0; k < 4; k++) cand[n * 4 + k] = si[k];
    }
}

// ---------------------------------------------------------------------------
// k4: fp64 exact re-evaluation of the 4 candidates per row (unchanged, proven).
// ---------------------------------------------------------------------------
__global__ void k_refine(const float* __restrict__ in, const float* __restrict__ cb,
                         const int* __restrict__ cand, int* __restrict__ idx_out,
                         float* __restrict__ idx_f) {
    int n = (blockIdx.x * blockDim.x + threadIdx.x) >> 6;
    int l = threadIdx.x & 63;
    if (n >= NROWS) return;
    int b = n >> 11, t = n & 2047;
    const float* xb = in + (long)b * DDIM * TT + t;
    double x0 = xb[(long)l * TT];
    double x1 = xb[(long)(l + 64) * TT];
    double best = -1e300;
    int bi = 0x7fffffff;
#pragma unroll
    for (int kk = 0; kk < 4; ++kk) {
        int c = cand[n * 4 + kk];
        const float* e = cb + (long)c * DDIM;
        double e0 = e[l], e1 = e[l + 64];
        double dot = x0 * e0 + x1 * e1;
        double nrm = e0 * e0 + e1 * e1;
#pragma unroll
        for (int s = 1; s < 64; s <<= 1) {
            dot += __shfl_xor(dot, s, 64);
            nrm += __shfl_xor(nrm, s, 64);
        }
        double sv = dot / fmax(sqrt(nrm), 1e-12);
        if (sv > best || (sv == best && c < bi)) { best = sv; bi = c; }
    }
    if (l == 0) {
        idx_out[n] = bi;
        idx_f[n] = (float)bi;
    }
}

// ---------------------------------------------------------------------------
// k5: out = x + (q - x) in [B,D,T] order + fp64 partial sums of (q-x)^2.
// ---------------------------------------------------------------------------
__global__ void k_out_loss(const float* __restrict__ in, const float* __restrict__ cb,
                           const int* __restrict__ idx, float* __restrict__ out,
                           double* __restrict__ part) {
    __shared__ double sd[256];
    double acc = 0.0;
    for (long e = (long)blockIdx.x * blockDim.x + threadIdx.x; e < ETOT;
         e += (long)gridDim.x * blockDim.x) {
        long t = e & 2047;
        long d = (e >> 11) & 127;
        long b = e >> 18;
        float xv = in[e];
        int n = (int)((b << 11) | t);
        float qv = cb[(long)idx[n] * DDIM + d];
        float diff = qv - xv;
        out[e] = xv + diff;
        acc += (double)diff * (double)diff;
    }
    sd[threadIdx.x] = acc;
    __syncthreads();
    for (int s = 128; s > 0; s >>= 1) {
        if (threadIdx.x < s) sd[threadIdx.x] += sd[threadIdx.x + s];
        __syncthreads();
    }
    if (threadIdx.x == 0) part[blockIdx.x] = sd[0];
}

__global__ void k_loss_final(const double* __restrict__ part, int np,
                             float* __restrict__ loss) {
    __shared__ double sd[256];
    double a = 0.0;
    for (int i = threadIdx.x; i < np; i += 256) a += part[i];
    sd[threadIdx.x] = a;
    __syncthreads();
    for (int s = 128; s > 0; s >>= 1) {
        if (threadIdx.x < s) sd[threadIdx.x] += sd[threadIdx.x + s];
        __syncthreads();
    }
    if (threadIdx.x == 0) {
        float m = (float)(sd[0] / (double)ETOT);
        loss[0] = m + 0.02f * m;
    }
}

// ---------------------------------------------------------------------------
extern "C" void kernel_launch(void* const* d_in, const int* in_sizes, int n_in,
                              void* d_out, int out_size, void* d_ws, size_t ws_size,
                              hipStream_t stream) {
    const float* inputs = (const float*)d_in[0];   // [16,128,2048] fp32
    const float* cb     = (const float*)d_in[1];   // [8192,128]    fp32
    float* outf = (float*)d_out;                   // [loss | out(B,D,T) | idx]

    char* ws = (char*)d_ws;
    _Float16* xh = (_Float16*)ws; ws += (long)NROWS * DDIM * 2;
    _Float16* eh = (_Float16*)ws; ws += (long)KCODES * DDIM * 2;
    int* cand    = (int*)ws;      ws += (long)NROWS * 4 * 4;
    int* idx     = (int*)ws;      ws += (long)NROWS * 4;
    double* part = (double*)ws;   ws += 2048 * 8;

    hipFuncSetAttribute((const void*)k_main,
                        hipFuncAttributeMaxDynamicSharedMemorySize, 49152);

    k_en_prep<<<dim3(2048), dim3(256), 0, stream>>>(cb, eh);
    k_x_prep<<<dim3(1024), dim3(256), 0, stream>>>(inputs, xh);
    k_main<<<dim3(512), dim3(512), 49152, stream>>>(xh, eh, cand);
    k_refine<<<dim3(8192), dim3(256), 0, stream>>>(inputs, cb, cand, idx,
                                                   outf + 1 + (long)ETOT);
    k_out_loss<<<dim3(2048), dim3(256), 0, stream>>>(inputs, cb, idx, outf + 1, part);
    k_loss_final<<<dim3(1), dim3(256), 0, stream>>>(part, 2048, outf);
}

// Round 5
// 180.240 us; speedup vs baseline: 1.6012x; 1.2917x over previous
//
#include <hip/hip_runtime.h>
#include <hip/hip_bf16.h>

#define NROWS 32768
#define KCODES 8192
#define DDIM 128
#define TT 2048
#define ETOT 4194304  // 16*128*2048

typedef __attribute__((ext_vector_type(8))) _Float16 f16x8;
typedef __attribute__((ext_vector_type(4))) float f32x4;

// pack: clear low 13 mantissa bits, OR in payload (= 8191 - code).
// float compare then orders by (truncated value, then LOWER code first).
__device__ __forceinline__ float pk(float v, int payload) {
    return __int_as_float((__float_as_int(v) & 0xFFFFE000) | payload);
}

// ---------------------------------------------------------------------------
// k1: normalize codebook rows, fp32 -> fp16, store in MFMA A-fragment order
//     per 128-code tile (32KB each): 8 cg-groups of 16 codes x 4 k-slices.
// code w: tile=w>>7, cg=(w>>4)&7, c=w&15 ; dim d: ks=d>>5, kq=(d>>3)&3, dr=d&7
// elem off = tile*16384 + ((ks*8+cg)*64 + kq*16 + c)*8 + dr
// ---------------------------------------------------------------------------
__global__ void k_en_prep(const float* __restrict__ cb,
                          _Float16* __restrict__ eh) {
    int w = (blockIdx.x * blockDim.x + threadIdx.x) >> 6;  // code id
    int l = threadIdx.x & 63;
    if (w >= KCODES) return;
    const float* row = cb + (long)w * DDIM;
    float v0 = row[l], v1 = row[l + 64];
    float ss = v0 * v0 + v1 * v1;
#pragma unroll
    for (int s = 1; s < 64; s <<= 1) ss += __shfl_xor(ss, s, 64);
    float inv = 1.0f / fmaxf(sqrtf(ss), 1e-12f);
    int tile = w >> 7, cg = (w >> 4) & 7, c = w & 15;
#pragma unroll
    for (int e = 0; e < 2; e++) {
        int d = l + e * 64;
        float v = (e ? v1 : v0) * inv;
        int ks = d >> 5, kq = (d >> 3) & 3, dr = d & 7;
        long off = (long)tile * 16384 + (((ks * 8 + cg) * 64) + kq * 16 + c) * 8 + dr;
        eh[off] = (_Float16)v;
    }
}

// ---------------------------------------------------------------------------
// k2: transpose inputs [B,D,T] -> xh [N=B*T, D] row-major fp16.
// ---------------------------------------------------------------------------
__global__ void k_x_prep(const float* __restrict__ in,
                         _Float16* __restrict__ xh) {
    __shared__ float tb[64][65];
    int bid = blockIdx.x;
    int tt0 = (bid & 31) * 64;
    int dd0 = ((bid >> 5) & 1) * 64;
    int b = bid >> 6;
    const float* base = in + (long)b * DDIM * TT;
    int tl = threadIdx.x & 63;
    int dg = threadIdx.x >> 6;
#pragma unroll
    for (int i = 0; i < 16; i++) {
        int dd = dg + i * 4;
        tb[dd][tl] = base[(long)(dd0 + dd) * TT + tt0 + tl];
    }
    __syncthreads();
    int dl = threadIdx.x & 63;
    int tg = threadIdx.x >> 6;
#pragma unroll
    for (int i = 0; i < 16; i++) {
        int t = tg + i * 4;
        long n = (long)b * TT + tt0 + t;
        xh[n * DDIM + dd0 + dl] = (_Float16)tb[dl][t];
    }
}

// ---------------------------------------------------------------------------
// k3 v5: fp16 GEMM + packed value-index selection, NO LDS staging.
// eh (2MB) is L2-resident (FETCH=12MB proved it) -> A-fragments read straight
// from global, 4 coalesced dwordx4 per tile per wave. No barriers; waves
// free-run. 512 blocks x 512 thr; 8 waves = 8 cg (16 codes each); block =
// 64 xrows (4 nf per wave). Tile = 128 codes, 64 tiles.
// Selection: pack (trunc-13-bit | 8191-code) -> pure min/max networks.
// Per lane: quad-top-2 -> top-3 stream + quad-second top-1 stream;
// epilogue: 128 packed entries/row -> global top-4 -> exact fp64 refine (k4).
// ---------------------------------------------------------------------------
__launch_bounds__(512, 4)
__global__ void k_main(const _Float16* __restrict__ xh,
                       const _Float16* __restrict__ eh,
                       int* __restrict__ cand) {
    __shared__ float mrg[128 * 65];  // epilogue merge area (33.3 KB)
    const int tid = threadIdx.x;
    const int l = tid & 63;
    const int cg = tid >> 6;         // 0..7 : 16-code group within tile
    const int col = l & 15, kq = l >> 4;
    const long rbase = (long)blockIdx.x * 64;

    // B-operand x-fragments in registers (loaded once): 4 nf x 4 ks
    f16x8 bx[4][4];
#pragma unroll
    for (int nf = 0; nf < 4; nf++) {
        long n = rbase + nf * 16 + col;
#pragma unroll
        for (int ks = 0; ks < 4; ks++)
            bx[nf][ks] = *(const f16x8*)(xh + n * DDIM + ks * 32 + kq * 8);
    }

    const float NEG = __int_as_float(0xFF800000);  // -inf (payload bits 0)
    float t1[4], t2[4], t3[4], u1[4];
#pragma unroll
    for (int i = 0; i < 4; i++) { t1[i] = t2[i] = t3[i] = u1[i] = NEG; }

    // payloads = 8191 - code ; code = t*128 + cg*16 + kq*4 + j
    int p0 = 8191 - (cg * 16 + kq * 4);
    int p1 = p0 - 1, p2 = p0 - 2, p3 = p0 - 3;

    const f16x8* ep = (const f16x8*)eh + cg * 64 + l;

#pragma unroll 2
    for (int t = 0; t < 64; ++t) {
        f16x8 ah0 = ep[0];
        f16x8 ah1 = ep[512];
        f16x8 ah2 = ep[1024];
        f16x8 ah3 = ep[1536];
        ep += 2048;

        f32x4 acc[4];
#pragma unroll
        for (int nf = 0; nf < 4; nf++) acc[nf] = (f32x4){0.f, 0.f, 0.f, 0.f};
#pragma unroll
        for (int nf = 0; nf < 4; nf++) {
            acc[nf] = __builtin_amdgcn_mfma_f32_16x16x32_f16(ah0, bx[nf][0], acc[nf], 0, 0, 0);
            acc[nf] = __builtin_amdgcn_mfma_f32_16x16x32_f16(ah1, bx[nf][1], acc[nf], 0, 0, 0);
            acc[nf] = __builtin_amdgcn_mfma_f32_16x16x32_f16(ah2, bx[nf][2], acc[nf], 0, 0, 0);
            acc[nf] = __builtin_amdgcn_mfma_f32_16x16x32_f16(ah3, bx[nf][3], acc[nf], 0, 0, 0);
        }

        // index-free selection on packed floats
#pragma unroll
        for (int nf = 0; nf < 4; nf++) {
            f32x4 a = acc[nf];
            float s0 = pk(a[0], p0), s1 = pk(a[1], p1);
            float s2 = pk(a[2], p2), s3 = pk(a[3], p3);
            float h01 = fmaxf(s0, s1), l01 = fminf(s0, s1);
            float h23 = fmaxf(s2, s3), l23 = fminf(s2, s3);
            float m1 = fmaxf(h01, h23);                                // quad max
            float m2 = fmaxf(fminf(h01, h23), fmaxf(l01, l23));        // quad 2nd
            float n1 = fminf(t1[nf], m1); t1[nf] = fmaxf(t1[nf], m1);  // top-3 insert
            float n2 = fminf(t2[nf], n1); t2[nf] = fmaxf(t2[nf], n1);
            t3[nf] = fmaxf(t3[nf], n2);
            u1[nf] = fmaxf(u1[nf], m2);                                // 2nd-stream top-1
        }
        p0 -= 128; p1 -= 128; p2 -= 128; p3 -= 128;
    }

    // epilogue: 128 entries per row (16 lane-positions x 8 waves... = cg*16+kq*4+v)
    const int e0 = cg * 16 + kq * 4;
#pragma unroll
    for (int nf = 0; nf < 4; nf++) {
        int row = nf * 16 + col;
        mrg[(e0 + 0) * 65 + row] = t1[nf];
        mrg[(e0 + 1) * 65 + row] = t2[nf];
        mrg[(e0 + 2) * 65 + row] = t3[nf];
        mrg[(e0 + 3) * 65 + row] = u1[nf];
    }
    __syncthreads();
    if (tid < 64) {
        float s1 = NEG, s2 = NEG, s3 = NEG, s4 = NEG;
#pragma unroll 8
        for (int e = 0; e < 128; e++) {
            float v = mrg[e * 65 + tid];
            float a1 = fminf(s1, v); s1 = fmaxf(s1, v);
            float a2 = fminf(s2, a1); s2 = fmaxf(s2, a1);
            float a3 = fminf(s3, a2); s3 = fmaxf(s3, a2);
            s4 = fmaxf(s4, a3);
        }
        long n = rbase + tid;
        cand[n * 4 + 0] = 8191 - (__float_as_int(s1) & 0x1FFF);
        cand[n * 4 + 1] = 8191 - (__float_as_int(s2) & 0x1FFF);
        cand[n * 4 + 2] = 8191 - (__float_as_int(s3) & 0x1FFF);
        cand[n * 4 + 3] = 8191 - (__float_as_int(s4) & 0x1FFF);
    }
}

// ---------------------------------------------------------------------------
// k4: fp64 exact re-evaluation of the 4 candidates per row (unchanged, proven).
// ---------------------------------------------------------------------------
__global__ void k_refine(const float* __restrict__ in, const float* __restrict__ cb,
                         const int* __restrict__ cand, int* __restrict__ idx_out,
                         float* __restrict__ idx_f) {
    int n = (blockIdx.x * blockDim.x + threadIdx.x) >> 6;
    int l = threadIdx.x & 63;
    if (n >= NROWS) return;
    int b = n >> 11, t = n & 2047;
    const float* xb = in + (long)b * DDIM * TT + t;
    double x0 = xb[(long)l * TT];
    double x1 = xb[(long)(l + 64) * TT];
    double best = -1e300;
    int bi = 0x7fffffff;
#pragma unroll
    for (int kk = 0; kk < 4; ++kk) {
        int c = cand[n * 4 + kk];
        const float* e = cb + (long)c * DDIM;
        double e0 = e[l], e1 = e[l + 64];
        double dot = x0 * e0 + x1 * e1;
        double nrm = e0 * e0 + e1 * e1;
#pragma unroll
        for (int s = 1; s < 64; s <<= 1) {
            dot += __shfl_xor(dot, s, 64);
            nrm += __shfl_xor(nrm, s, 64);
        }
        double sv = dot / fmax(sqrt(nrm), 1e-12);
        if (sv > best || (sv == best && c < bi)) { best = sv; bi = c; }
    }
    if (l == 0) {
        idx_out[n] = bi;
        idx_f[n] = (float)bi;
    }
}

// ---------------------------------------------------------------------------
// k5: out = x + (q - x) in [B,D,T] order + fp64 partial sums of (q-x)^2.
// ---------------------------------------------------------------------------
__global__ void k_out_loss(const float* __restrict__ in, const float* __restrict__ cb,
                           const int* __restrict__ idx, float* __restrict__ out,
                           double* __restrict__ part) {
    __shared__ double sd[256];
    double acc = 0.0;
    for (long e = (long)blockIdx.x * blockDim.x + threadIdx.x; e < ETOT;
         e += (long)gridDim.x * blockDim.x) {
        long t = e & 2047;
        long d = (e >> 11) & 127;
        long b = e >> 18;
        float xv = in[e];
        int n = (int)((b << 11) | t);
        float qv = cb[(long)idx[n] * DDIM + d];
        float diff = qv - xv;
        out[e] = xv + diff;
        acc += (double)diff * (double)diff;
    }
    sd[threadIdx.x] = acc;
    __syncthreads();
    for (int s = 128; s > 0; s >>= 1) {
        if (threadIdx.x < s) sd[threadIdx.x] += sd[threadIdx.x + s];
        __syncthreads();
    }
    if (threadIdx.x == 0) part[blockIdx.x] = sd[0];
}

__global__ void k_loss_final(const double* __restrict__ part, int np,
                             float* __restrict__ loss) {
    __shared__ double sd[256];
    double a = 0.0;
    for (int i = threadIdx.x; i < np; i += 256) a += part[i];
    sd[threadIdx.x] = a;
    __syncthreads();
    for (int s = 128; s > 0; s >>= 1) {
        if (threadIdx.x < s) sd[threadIdx.x] += sd[threadIdx.x + s];
        __syncthreads();
    }
    if (threadIdx.x == 0) {
        float m = (float)(sd[0] / (double)ETOT);
        loss[0] = m + 0.02f * m;
    }
}

// ---------------------------------------------------------------------------
extern "C" void kernel_launch(void* const* d_in, const int* in_sizes, int n_in,
                              void* d_out, int out_size, void* d_ws, size_t ws_size,
                              hipStream_t stream) {
    const float* inputs = (const float*)d_in[0];   // [16,128,2048] fp32
    const float* cb     = (const float*)d_in[1];   // [8192,128]    fp32
    float* outf = (float*)d_out;                   // [loss | out(B,D,T) | idx]

    char* ws = (char*)d_ws;
    _Float16* xh = (_Float16*)ws; ws += (long)NROWS * DDIM * 2;
    _Float16* eh = (_Float16*)ws; ws += (long)KCODES * DDIM * 2;
    int* cand    = (int*)ws;      ws += (long)NROWS * 4 * 4;
    int* idx     = (int*)ws;      ws += (long)NROWS * 4;
    double* part = (double*)ws;   ws += 2048 * 8;

    k_en_prep<<<dim3(2048), dim3(256), 0, stream>>>(cb, eh);
    k_x_prep<<<dim3(1024), dim3(256), 0, stream>>>(inputs, xh);
    k_main<<<dim3(512), dim3(512), 0, stream>>>(xh, eh, cand);
    k_refine<<<dim3(8192), dim3(256), 0, stream>>>(inputs, cb, cand, idx,
                                                   outf + 1 + (long)ETOT);
    k_out_loss<<<dim3(2048), dim3(256), 0, stream>>>(inputs, cb, idx, outf + 1, part);
    k_loss_final<<<dim3(1), dim3(256), 0, stream>>>(part, 2048, outf);
}